// Round 1
// baseline (1066.234 us; speedup 1.0000x reference)
//
#include <hip/hip_runtime.h>

#define NB 4
#define NC 64
#define NHW 128
#define NWIN 31
#define NL (NWIN*NWIN)

// ---------------- SE: global average pool per (b,c) ----------------
__global__ void k_pool(const float* __restrict__ high, float* __restrict__ pooled) {
    int bc = blockIdx.x;                       // 0..255 = b*64+c
    const float* src = high + (size_t)bc * (NHW*NHW);
    float s = 0.f;
    for (int i = threadIdx.x; i < NHW*NHW; i += 256) s += src[i];
    for (int off = 32; off > 0; off >>= 1) s += __shfl_down(s, off);
    __shared__ float red[4];
    int lane = threadIdx.x & 63, wv = threadIdx.x >> 6;
    if (lane == 0) red[wv] = s;
    __syncthreads();
    if (threadIdx.x == 0)
        pooled[bc] = (red[0] + red[1] + red[2] + red[3]) * (1.f / (NHW*NHW));
}

// ---------------- SE: gate s[b,c] ----------------
__global__ void k_gate(const float* __restrict__ pooled,
                       const float* __restrict__ w10, const float* __restrict__ w20,
                       const float* __restrict__ w11, const float* __restrict__ w21,
                       const float* __restrict__ w12, const float* __restrict__ w22,
                       float* __restrict__ sgate) {
    __shared__ float pl[256];
    int t = threadIdx.x;
    pl[t] = pooled[t];
    __syncthreads();
    int b = t >> 6, c = t & 63;
    const float* w1; const float* w2; int o0, gc;
    if (c < 22)      { w1 = w10; w2 = w20; o0 = 0;  gc = 22; }
    else if (c < 43) { w1 = w11; w2 = w21; o0 = 22; gc = 21; }
    else             { w1 = w12; w2 = w22; o0 = 43; gc = 21; }
    float a = 0.f;
    for (int k = 0; k < gc; ++k) a += pl[b*64 + o0 + k] * w1[k];
    a = fmaxf(a, 0.f);
    float z = a * w2[c - o0];
    sgate[t] = 1.f / (1.f + __expf(-z));
}

// ---------------- windowed cross attention, both directions ----------------
// one block per (b, window). 256 threads. thread (h = t/64, n = t%64) owns
// attention row n of head h (row-softmax entirely in registers).
__global__ __launch_bounds__(256, 2) void k_attn(
    const float* __restrict__ low, const float* __restrict__ high,
    const float* __restrict__ w_ql, const float* __restrict__ w_kh, const float* __restrict__ w_vh,
    const float* __restrict__ w_qh, const float* __restrict__ w_kl, const float* __restrict__ w_vl,
    const float* __restrict__ sgate, float* __restrict__ out /* [2][B][C][H][W] fold acc */) {
    __shared__ float Xl[4096], Xh[4096], Ksh[4096], Vsh[4096];   // 64 KB
    int blk = blockIdx.x;
    int b = blk / NL, l = blk - b*NL;
    int row0 = (l / NWIN) * 4, col0 = (l - (l / NWIN)*NWIN) * 4;
    int t = threadIdx.x;
    int n = t & 63, h = t >> 6, cb = h << 4;

    // stage tiles: X[c][n] layout, n = window pixel (wr*8+wc)
    for (int e = t; e < 4096; e += 256) {
        int c = e >> 6, p = e & 63;
        size_t gi = (((size_t)b*NC + c)*NHW + row0 + (p >> 3))*NHW + col0 + (p & 7);
        Xl[e] = low[gi];
        Xh[e] = high[gi] * sgate[b*NC + c];
    }
    __syncthreads();

    for (int pass = 0; pass < 2; ++pass) {
        const float* Xq  = pass ? Xh : Xl;
        const float* Xkv = pass ? Xl : Xh;
        const float* Wq  = pass ? w_qh : w_ql;
        const float* Wk  = pass ? w_kl : w_kh;
        const float* Wv  = pass ? w_vl : w_vh;
        float* accp = out + (size_t)pass * ((size_t)NB*NC*NHW*NHW);

        // K = Wk·Xkv, V = Wv·Xkv  (thread computes rows cb..cb+15 at column n)
        float xc[64];
        #pragma unroll
        for (int k = 0; k < 64; ++k) xc[k] = Xkv[k*64 + n];
        for (int j = 0; j < 16; ++j) {
            const float* wk = Wk + (cb + j)*64;
            const float* wv = Wv + (cb + j)*64;
            float ak = 0.f, av = 0.f;
            #pragma unroll
            for (int k = 0; k < 64; ++k) { ak = fmaf(wk[k], xc[k], ak); av = fmaf(wv[k], xc[k], av); }
            Ksh[(cb + j)*64 + n] = ak;
            Vsh[(cb + j)*64 + n] = av;
        }
        // Q rows for this thread's head, kept in registers
        float ql[16];
        #pragma unroll
        for (int k = 0; k < 64; ++k) xc[k] = Xq[k*64 + n];
        #pragma unroll
        for (int j = 0; j < 16; ++j) {
            const float* wq = Wq + (cb + j)*64;
            float a = 0.f;
            #pragma unroll
            for (int k = 0; k < 64; ++k) a = fmaf(wq[k], xc[k], a);
            ql[j] = a;
        }
        __syncthreads();

        // S row: S[n,m] = sum_d Q[d,n]K[d,m] * 0.25
        float srow[64];
        #pragma unroll
        for (int m = 0; m < 64; ++m) {
            float s = 0.f;
            #pragma unroll
            for (int j = 0; j < 16; ++j) s = fmaf(ql[j], Ksh[(cb + j)*64 + m], s);
            srow[m] = s * 0.25f;
        }
        float mx = srow[0];
        #pragma unroll
        for (int m = 1; m < 64; ++m) mx = fmaxf(mx, srow[m]);
        float ssum = 0.f;
        #pragma unroll
        for (int m = 0; m < 64; ++m) { float e = __expf(srow[m] - mx); srow[m] = e; ssum += e; }
        float inv = 1.f / ssum;

        // O[d,n] = sum_m A[n,m] V[d,m]; overlap-add (fold) via atomics
        int r = row0 + (n >> 3), cc = col0 + (n & 7);
        for (int j = 0; j < 16; ++j) {
            float o = 0.f;
            #pragma unroll
            for (int m = 0; m < 64; ++m) o = fmaf(srow[m], Vsh[(cb + j)*64 + m], o);
            atomicAdd(&accp[(((size_t)b*NC + cb + j)*NHW + r)*NHW + cc], o * inv);
        }
        __syncthreads();   // protect Ksh/Vsh before next pass overwrites
    }
}

// ---------------- mask + final 1x1 projection + residual (in place) ----------------
__device__ __forceinline__ float rowcount(int x) {
    int lo = (x >= 7) ? ((x - 4) >> 2) : 0;   // ceil((x-7)/4), clamped at 0 (max is 30)
    int hi = x >> 2; hi = hi > 30 ? 30 : hi;
    return (float)(hi - lo + 1);
}

__global__ __launch_bounds__(256) void k_final(const float* __restrict__ resid,
                                               const float* __restrict__ wproj,
                                               float* __restrict__ acc) {
    int blk = blockIdx.x;                    // b*256 + hrow*2 + wtile
    int b = blk >> 8;
    int hrow = (blk >> 1) & 127;
    int w0 = (blk & 1) << 6;
    __shared__ float X[4096];
    int t = threadIdx.x;
    float rh = rowcount(hrow);
    for (int e = t; e < 4096; e += 256) {
        int c = e >> 6, p = e & 63;
        float m = rh * rowcount(w0 + p);
        X[e] = acc[(((size_t)b*NC + c)*NHW + hrow)*NHW + w0 + p] * (1.f / m);
    }
    __syncthreads();
    int p = t & 63, ob = (t >> 6) << 4;
    float xc[64];
    #pragma unroll
    for (int k = 0; k < 64; ++k) xc[k] = X[k*64 + p];
    for (int j = 0; j < 16; ++j) {
        const float* wr = wproj + (ob + j)*64;
        float a = 0.f;
        #pragma unroll
        for (int k = 0; k < 64; ++k) a = fmaf(wr[k], xc[k], a);
        size_t gi = (((size_t)b*NC + ob + j)*NHW + hrow)*NHW + w0 + p;
        acc[gi] = resid[gi] + a;
    }
}

extern "C" void kernel_launch(void* const* d_in, const int* in_sizes, int n_in,
                              void* d_out, int out_size, void* d_ws, size_t ws_size,
                              hipStream_t stream) {
    const float* low  = (const float*)d_in[0];
    const float* high = (const float*)d_in[1];
    const float* w_ql = (const float*)d_in[2];
    const float* w_kh = (const float*)d_in[3];
    const float* w_vh = (const float*)d_in[4];
    const float* w_qh = (const float*)d_in[5];
    const float* w_kl = (const float*)d_in[6];
    const float* w_vl = (const float*)d_in[7];
    const float* w_pl = (const float*)d_in[8];
    const float* w_ph = (const float*)d_in[9];
    float* out = (float*)d_out;
    float* pooled = (float*)d_ws;      // 256 floats
    float* sgate  = pooled + 256;      // 256 floats

    // d_out doubles as the fold accumulator; zero it (harness poisons with 0xAA)
    hipMemsetAsync(d_out, 0, (size_t)out_size * sizeof(float), stream);

    k_pool<<<dim3(NB*NC), dim3(256), 0, stream>>>(high, pooled);
    k_gate<<<dim3(1), dim3(256), 0, stream>>>(pooled,
        (const float*)d_in[10], (const float*)d_in[11],
        (const float*)d_in[12], (const float*)d_in[13],
        (const float*)d_in[14], (const float*)d_in[15], sgate);
    k_attn<<<dim3(NB*NL), dim3(256), 0, stream>>>(low, high,
        w_ql, w_kh, w_vh, w_qh, w_kl, w_vl, sgate, out);
    k_final<<<dim3(NB*NHW*2), dim3(256), 0, stream>>>(low,  w_pl, out);
    k_final<<<dim3(NB*NHW*2), dim3(256), 0, stream>>>(high, w_ph,
        out + (size_t)NB*NC*NHW*NHW);
}

// Round 2
// 485.755 us; speedup vs baseline: 2.1950x; 2.1950x over previous
//
#include <hip/hip_runtime.h>

typedef short short8 __attribute__((ext_vector_type(8)));
typedef short short4v __attribute__((ext_vector_type(4)));
typedef float f4 __attribute__((ext_vector_type(4)));

#define NB 4
#define NHW 128
#define NWIN 31
#define NL (NWIN*NWIN)
// XOR-swizzled LDS layout: row-major 64-wide, 8-col blocks swizzled by row&7.
// Frag reads (8 consecutive cols, col0 % 8 == 0) stay contiguous 16B; bank
// groups spread across rows -> conflict-free b128.
#define SW(r,c) (((r)<<6) + (((((c)>>3) ^ ((r)&7))<<3) | ((c)&7)))
#define MFMA(a,b,c) __builtin_amdgcn_mfma_f32_16x16x32_bf16(a,b,c,0,0,0)

__device__ __forceinline__ short f2bf(float f) {
    unsigned u = __float_as_uint(f);
    u += 0x7fffu + ((u >> 16) & 1u);   // RNE; inputs never NaN/inf
    return (short)(u >> 16);
}
__device__ __forceinline__ float bf2f(short v) {
    return __uint_as_float(((unsigned)(unsigned short)v) << 16);
}

// ---------------- SE: global average pool per (b,c) ----------------
__global__ void k_pool(const float* __restrict__ high, float* __restrict__ pooled) {
    int bc = blockIdx.x;
    const float* src = high + (size_t)bc * (NHW*NHW);
    float s = 0.f;
    for (int i = threadIdx.x; i < NHW*NHW; i += 256) s += src[i];
    for (int off = 32; off > 0; off >>= 1) s += __shfl_down(s, off);
    __shared__ float red[4];
    int lane = threadIdx.x & 63, wv = threadIdx.x >> 6;
    if (lane == 0) red[wv] = s;
    __syncthreads();
    if (threadIdx.x == 0)
        pooled[bc] = (red[0] + red[1] + red[2] + red[3]) * (1.f / (NHW*NHW));
}

// ---------------- SE: gate s[b,c] ----------------
__global__ void k_gate(const float* __restrict__ pooled,
                       const float* __restrict__ w10, const float* __restrict__ w20,
                       const float* __restrict__ w11, const float* __restrict__ w21,
                       const float* __restrict__ w12, const float* __restrict__ w22,
                       float* __restrict__ sgate) {
    __shared__ float pl[256];
    int t = threadIdx.x;
    pl[t] = pooled[t];
    __syncthreads();
    int b = t >> 6, c = t & 63;
    const float* w1; const float* w2; int o0, gc;
    if (c < 22)      { w1 = w10; w2 = w20; o0 = 0;  gc = 22; }
    else if (c < 43) { w1 = w11; w2 = w21; o0 = 22; gc = 21; }
    else             { w1 = w12; w2 = w22; o0 = 43; gc = 21; }
    float a = 0.f;
    for (int k = 0; k < gc; ++k) a += pl[b*64 + o0 + k] * w1[k];
    a = fmaxf(a, 0.f);
    float z = a * w2[c - o0];
    sgate[t] = 1.f / (1.f + __expf(-z));
}

// X fragment loader from global: element X[c][np] for lane (l16, quad), j=0..7.
// Serves BOTH A-frags (A[np][c], row np=n0+l16) and B-frags (B[c][np], col np=n0+l16)
// since both lane layouts read the same element.
__device__ __forceinline__ short8 loadX(const float* __restrict__ src, const float* sg, bool gate,
                                        int b, int row0, int col0, int n0, int c0,
                                        int l16, int quad) {
    int np = n0 + l16;
    int rr = row0 + (np >> 3), cc = col0 + (np & 7);
    int cb = c0 + quad * 8;
    const float* p = src + (((size_t)(b * 64 + cb) * NHW + rr) * NHW + cc);
    short8 a;
    #pragma unroll
    for (int j = 0; j < 8; ++j) {
        float v = p[(size_t)j * (NHW*NHW)];
        if (gate) v *= sg[cb + j];
        a[j] = f2bf(v);
    }
    return a;
}

// Weight fragment from global (row-major W[o][c]); B-frag B[c][o] (col o=o0+l16)
// or A-frag A[o][c] (row o=o0+l16) -- same element mapping.
__device__ __forceinline__ short8 loadW(const float* __restrict__ Wg, int o0, int c0,
                                        int l16, int quad) {
    const float* p = Wg + (o0 + l16) * 64 + c0 + quad * 8;
    float4 x = *(const float4*)p;
    float4 y = *(const float4*)(p + 4);
    short8 r;
    r[0]=f2bf(x.x); r[1]=f2bf(x.y); r[2]=f2bf(x.z); r[3]=f2bf(x.w);
    r[4]=f2bf(y.x); r[5]=f2bf(y.y); r[6]=f2bf(y.z); r[7]=f2bf(y.w);
    return r;
}

// write C/D tile (rows rbase+quad*4+r, col cbase+l16) to swizzled LDS
__device__ __forceinline__ void writeD(short* buf, f4 acc, int rbase, int cbase,
                                       int l16, int quad) {
    #pragma unroll
    for (int r = 0; r < 4; ++r)
        buf[SW(rbase + quad*4 + r, cbase + l16)] = f2bf(acc[r]);
}

// windows covering coordinate x (ws=8, stride 4)
__device__ __forceinline__ float rowcount(int x) {
    int lo = (x >= 7) ? ((x - 4) >> 2) : 0;
    int hi = x >> 2; hi = hi > 30 ? 30 : hi;
    return (float)(hi - lo + 1);
}

// ---------------- windowed cross attention, MFMA ----------------
// MODE 0: store per-window O (bf16) to scratch [dir][b][l][np][c]
// MODE 1: atomicAdd into fold accumulator (d_out)
// MODE 2: plain store into fold accumulator (parity (0,0): windows tile exactly)
template<int MODE>
__global__ __launch_bounds__(256, 4) void k_attn(
    const float* __restrict__ low, const float* __restrict__ high,
    const float* __restrict__ w_ql, const float* __restrict__ w_kh, const float* __restrict__ w_vh,
    const float* __restrict__ w_qh, const float* __restrict__ w_kl, const float* __restrict__ w_vl,
    const float* __restrict__ sgate, float* __restrict__ outp, short* __restrict__ scr,
    int pr, int pc, int nr, int nc) {
    __shared__ __align__(16) short QT[4096];   // Q^T [np][c]
    __shared__ __align__(16) short KT[4096];   // K^T [np][c]
    __shared__ __align__(16) short Vs[4096];   // V   [c][np]
    __shared__ __align__(16) short Pb[8192];   // per-wave P [32 rows][64 m] (pair-local)
    __shared__ float sg[64];
    int bidx = blockIdx.x;
    int nrc = nr * nc;
    int b = bidx / nrc; int rem = bidx - b * nrc;
    int wr = rem / nc, wc = rem - (rem / nc) * nc;
    if (MODE != 0) { wr = pr + 2*wr; wc = pc + 2*wc; }
    int l = wr * NWIN + wc;
    int row0 = wr * 4, col0 = wc * 4;
    int t = threadIdx.x, w = t >> 6, ln = t & 63, l16 = ln & 15, quad = ln >> 4;
    if (t < 64) sg[t] = sgate[b*64 + t];
    __syncthreads();
    short* Pw = Pb + w * 2048;

    for (int pass = 0; pass < 2; ++pass) {
        const float* Xq  = pass ? high : low;
        const float* Xkv = pass ? low  : high;
        const float* Wq  = pass ? w_qh : w_ql;
        const float* Wk  = pass ? w_kl : w_kh;
        const float* Wv  = pass ? w_vl : w_vh;
        bool gq = (pass == 1), gkv = (pass == 0);   // high plane is gated

        // --- projections: Q^T = Xq^T * Wq^T, K^T = Xkv^T * Wk^T, V = Wv * Xkv ---
        {
            short8 xa0 = loadX(Xq, sg, gq, b, row0, col0, 16*w, 0,  l16, quad);
            short8 xa1 = loadX(Xq, sg, gq, b, row0, col0, 16*w, 32, l16, quad);
            #pragma unroll
            for (int ct = 0; ct < 4; ++ct) {
                f4 acc = {0.f,0.f,0.f,0.f};
                acc = MFMA(xa0, loadW(Wq, ct*16, 0,  l16, quad), acc);
                acc = MFMA(xa1, loadW(Wq, ct*16, 32, l16, quad), acc);
                writeD(QT, acc, 16*w, ct*16, l16, quad);
            }
            short8 ka0 = loadX(Xkv, sg, gkv, b, row0, col0, 16*w, 0,  l16, quad);
            short8 ka1 = loadX(Xkv, sg, gkv, b, row0, col0, 16*w, 32, l16, quad);
            #pragma unroll
            for (int ct = 0; ct < 4; ++ct) {
                f4 acc = {0.f,0.f,0.f,0.f};
                acc = MFMA(ka0, loadW(Wk, ct*16, 0,  l16, quad), acc);
                acc = MFMA(ka1, loadW(Wk, ct*16, 32, l16, quad), acc);
                writeD(KT, acc, 16*w, ct*16, l16, quad);
            }
            short8 wv0 = loadW(Wv, 16*w, 0,  l16, quad);
            short8 wv1 = loadW(Wv, 16*w, 32, l16, quad);
            #pragma unroll
            for (int nt = 0; nt < 4; ++nt) {
                f4 acc = {0.f,0.f,0.f,0.f};
                acc = MFMA(wv0, loadX(Xkv, sg, gkv, b, row0, col0, nt*16, 0,  l16, quad), acc);
                acc = MFMA(wv1, loadX(Xkv, sg, gkv, b, row0, col0, nt*16, 32, l16, quad), acc);
                writeD(Vs, acc, 16*w, nt*16, l16, quad);
            }
        }
        __syncthreads();

        // --- attention: head h = w; S = Q_h^T K_h (K=32, zero-padded d=16) ---
        int h = w;
        short8 qa[4], kb[4];
        #pragma unroll
        for (int i = 0; i < 4; ++i) {
            if (quad < 2) {
                qa[i] = *(const short8*)(QT + SW(i*16 + l16, 16*h + quad*8));
                kb[i] = *(const short8*)(KT + SW(i*16 + l16, 16*h + quad*8));
            } else {
                short8 z = {0,0,0,0,0,0,0,0};
                qa[i] = z; kb[i] = z;
            }
        }
        short8 va0 = *(const short8*)(Vs + SW(16*h + l16, quad*8));
        short8 va1 = *(const short8*)(Vs + SW(16*h + l16, 32 + quad*8));

        #pragma unroll
        for (int pair = 0; pair < 2; ++pair) {
            f4 s[2][4];
            #pragma unroll
            for (int ntl = 0; ntl < 2; ++ntl)
                #pragma unroll
                for (int mt = 0; mt < 4; ++mt) {
                    f4 acc = {0.f,0.f,0.f,0.f};
                    s[ntl][mt] = MFMA(qa[pair*2 + ntl], kb[mt], acc);
                }
            // row softmax: row n = pair*32+ntl*16+quad*4+r, across mt regs + 16 lanes
            #pragma unroll
            for (int ntl = 0; ntl < 2; ++ntl) {
                f4 mx = s[ntl][0];
                #pragma unroll
                for (int mt = 1; mt < 4; ++mt)
                    #pragma unroll
                    for (int r = 0; r < 4; ++r) mx[r] = fmaxf(mx[r], s[ntl][mt][r]);
                #pragma unroll
                for (int d = 1; d < 16; d <<= 1)
                    #pragma unroll
                    for (int r = 0; r < 4; ++r) mx[r] = fmaxf(mx[r], __shfl_xor(mx[r], d));
                f4 sum = {0.f,0.f,0.f,0.f};
                #pragma unroll
                for (int mt = 0; mt < 4; ++mt)
                    #pragma unroll
                    for (int r = 0; r < 4; ++r) {
                        float e = __expf((s[ntl][mt][r] - mx[r]) * 0.25f);
                        s[ntl][mt][r] = e; sum[r] += e;
                    }
                #pragma unroll
                for (int d = 1; d < 16; d <<= 1)
                    #pragma unroll
                    for (int r = 0; r < 4; ++r) sum[r] += __shfl_xor(sum[r], d);
                #pragma unroll
                for (int r = 0; r < 4; ++r) sum[r] = 1.f / sum[r];
                #pragma unroll
                for (int mt = 0; mt < 4; ++mt)
                    #pragma unroll
                    for (int r = 0; r < 4; ++r)
                        Pw[SW(ntl*16 + quad*4 + r, mt*16 + l16)] = f2bf(s[ntl][mt][r] * sum[r]);
            }
            // O tile for this pair: O[d][np] = V_h * P^T
            #pragma unroll
            for (int ntl = 0; ntl < 2; ++ntl) {
                f4 acc = {0.f,0.f,0.f,0.f};
                acc = MFMA(va0, *(const short8*)(Pw + SW(ntl*16 + l16, quad*8)), acc);
                acc = MFMA(va1, *(const short8*)(Pw + SW(ntl*16 + l16, 32 + quad*8)), acc);
                int np = pair*32 + ntl*16 + l16;
                if (MODE == 0) {
                    size_t base = (((size_t)((pass*NB + b)*NL + l) * 64 + np) * 64) + 16*h + quad*4;
                    short4v sv;
                    #pragma unroll
                    for (int r = 0; r < 4; ++r) sv[r] = f2bf(acc[r]);
                    *(short4v*)(scr + base) = sv;
                } else {
                    int rr = row0 + (np >> 3), cc = col0 + (np & 7);
                    float* op = outp + (size_t)pass * ((size_t)NB*64*NHW*NHW);
                    #pragma unroll
                    for (int r = 0; r < 4; ++r) {
                        size_t gi = (((size_t)(b*64 + 16*h + quad*4 + r)) * NHW + rr) * NHW + cc;
                        if (MODE == 2) op[gi] = acc[r];
                        else atomicAdd(&op[gi], acc[r]);
                    }
                }
            }
        }
        __syncthreads();
    }
}

// ---------------- fold(gather) + mask + 1x1 proj + residual (scratch path) ----------------
__global__ __launch_bounds__(256) void k_gather(
    const short* __restrict__ scr, const float* __restrict__ resid,
    const float* __restrict__ wproj, float* __restrict__ outp) {
    __shared__ __align__(16) short G[8192];    // G[p][c], swizzled
    int bidx = blockIdx.x; int b = bidx >> 7, hh = bidx & 127;
    int t = threadIdx.x;
    int p = t >> 1, c0 = (t & 1) * 32;
    float g[32];
    #pragma unroll
    for (int k = 0; k < 32; ++k) g[k] = 0.f;
    int wrlo = (hh >= 8) ? ((hh - 4) >> 2) : 0;
    int wrhi = hh >> 2; if (wrhi > 30) wrhi = 30;
    int wclo = (p >= 8) ? ((p - 4) >> 2) : 0;
    int wchi = p >> 2; if (wchi > 30) wchi = 30;
    for (int wr = wrlo; wr <= wrhi; ++wr)
        for (int wc = wclo; wc <= wchi; ++wc) {
            int np = (hh - 4*wr) * 8 + (p - 4*wc);
            const short* src = scr + (((size_t)(b*NL + wr*NWIN + wc) * 64 + np) * 64) + c0;
            #pragma unroll
            for (int k4 = 0; k4 < 4; ++k4) {
                short8 v = *(const short8*)(src + k4*8);
                #pragma unroll
                for (int j = 0; j < 8; ++j) g[k4*8 + j] += bf2f(v[j]);
            }
        }
    float inv = 1.f / (rowcount(hh) * rowcount(p));
    #pragma unroll
    for (int k4 = 0; k4 < 4; ++k4) {
        short8 v;
        #pragma unroll
        for (int j = 0; j < 8; ++j) v[j] = f2bf(g[k4*8 + j] * inv);
        *(short8*)(G + SW(p, c0 + k4*8)) = v;
    }
    __syncthreads();
    int w = t >> 6, ln = t & 63, l16 = ln & 15, quad = ln >> 4;
    short8 wa0 = loadW(wproj, 16*w, 0,  l16, quad);
    short8 wa1 = loadW(wproj, 16*w, 32, l16, quad);
    #pragma unroll
    for (int pt = 0; pt < 8; ++pt) {
        f4 acc = {0.f,0.f,0.f,0.f};
        acc = MFMA(wa0, *(const short8*)(G + SW(pt*16 + l16, quad*8)), acc);
        acc = MFMA(wa1, *(const short8*)(G + SW(pt*16 + l16, 32 + quad*8)), acc);
        #pragma unroll
        for (int r = 0; r < 4; ++r) {
            size_t gi = (((size_t)(b*64 + 16*w + quad*4 + r)) * NHW + hh) * NHW + pt*16 + l16;
            outp[gi] = resid[gi] + acc[r];
        }
    }
}

// ---------------- fallback: mask + 1x1 proj + residual (in place over fold acc) ----------------
__global__ __launch_bounds__(256) void k_final(const float* __restrict__ resid,
                                               const float* __restrict__ wproj,
                                               float* __restrict__ acc) {
    int blk = blockIdx.x;
    int b = blk >> 8;
    int hrow = (blk >> 1) & 127;
    int w0 = (blk & 1) << 6;
    __shared__ float X[4096];
    int t = threadIdx.x;
    float rh = rowcount(hrow);
    for (int e = t; e < 4096; e += 256) {
        int c = e >> 6, p = e & 63;
        float m = rh * rowcount(w0 + p);
        X[e] = acc[(((size_t)b*64 + c)*NHW + hrow)*NHW + w0 + p] * (1.f / m);
    }
    __syncthreads();
    int p = t & 63, ob = (t >> 6) << 4;
    float xc[64];
    #pragma unroll
    for (int k = 0; k < 64; ++k) xc[k] = X[k*64 + p];
    for (int j = 0; j < 16; ++j) {
        const float* wr = wproj + (ob + j)*64;
        float a = 0.f;
        #pragma unroll
        for (int k = 0; k < 64; ++k) a = fmaf(wr[k], xc[k], a);
        size_t gi = (((size_t)b*64 + ob + j)*NHW + hrow)*NHW + w0 + p;
        acc[gi] = resid[gi] + a;
    }
}

extern "C" void kernel_launch(void* const* d_in, const int* in_sizes, int n_in,
                              void* d_out, int out_size, void* d_ws, size_t ws_size,
                              hipStream_t stream) {
    const float* low  = (const float*)d_in[0];
    const float* high = (const float*)d_in[1];
    const float* w_ql = (const float*)d_in[2];
    const float* w_kh = (const float*)d_in[3];
    const float* w_vh = (const float*)d_in[4];
    const float* w_qh = (const float*)d_in[5];
    const float* w_kl = (const float*)d_in[6];
    const float* w_vl = (const float*)d_in[7];
    const float* w_pl = (const float*)d_in[8];
    const float* w_ph = (const float*)d_in[9];
    float* out = (float*)d_out;
    float* pooled = (float*)d_ws;
    float* sgate  = pooled + 256;
    short* scr = (short*)((char*)d_ws + 4096);
    size_t dir_elems = (size_t)NB * NL * 64 * 64;             // per-direction scratch (bf16)
    size_t need = 4096 + 2 * dir_elems * sizeof(short);

    k_pool<<<dim3(NB*64), dim3(256), 0, stream>>>(high, pooled);
    k_gate<<<dim3(1), dim3(256), 0, stream>>>(pooled,
        (const float*)d_in[10], (const float*)d_in[11],
        (const float*)d_in[12], (const float*)d_in[13],
        (const float*)d_in[14], (const float*)d_in[15], sgate);

    if (ws_size >= need) {
        k_attn<0><<<dim3(NB*NL), dim3(256), 0, stream>>>(low, high,
            w_ql, w_kh, w_vh, w_qh, w_kl, w_vl, sgate, nullptr, scr, 0, 0, NWIN, NWIN);
        k_gather<<<dim3(NB*NHW), dim3(256), 0, stream>>>(scr, low, w_pl, out);
        k_gather<<<dim3(NB*NHW), dim3(256), 0, stream>>>(scr + dir_elems, high, w_ph,
            out + (size_t)NB*64*NHW*NHW);
    } else {
        // parity-split fold: parity (0,0) windows tile the plane -> plain store,
        // remaining parities atomicAdd (ordered by stream).
        k_attn<2><<<dim3(NB*16*16), dim3(256), 0, stream>>>(low, high,
            w_ql, w_kh, w_vh, w_qh, w_kl, w_vl, sgate, out, nullptr, 0, 0, 16, 16);
        k_attn<1><<<dim3(NB*16*15), dim3(256), 0, stream>>>(low, high,
            w_ql, w_kh, w_vh, w_qh, w_kl, w_vl, sgate, out, nullptr, 0, 1, 16, 15);
        k_attn<1><<<dim3(NB*15*16), dim3(256), 0, stream>>>(low, high,
            w_ql, w_kh, w_vh, w_qh, w_kl, w_vl, sgate, out, nullptr, 1, 0, 15, 16);
        k_attn<1><<<dim3(NB*15*15), dim3(256), 0, stream>>>(low, high,
            w_ql, w_kh, w_vh, w_qh, w_kl, w_vl, sgate, out, nullptr, 1, 1, 15, 15);
        k_final<<<dim3(NB*NHW*2), dim3(256), 0, stream>>>(low,  w_pl, out);
        k_final<<<dim3(NB*NHW*2), dim3(256), 0, stream>>>(high, w_ph,
            out + (size_t)NB*64*NHW*NHW);
    }
}

// Round 3
// 283.938 us; speedup vs baseline: 3.7552x; 1.7108x over previous
//
#include <hip/hip_runtime.h>

typedef short short8 __attribute__((ext_vector_type(8)));
typedef short short4v __attribute__((ext_vector_type(4)));
typedef float f4 __attribute__((ext_vector_type(4)));

#define NB 4
#define NHW 128
#define NWIN 31
#define NL (NWIN*NWIN)
// 64-wide row, 8-col-block XOR swizzle (conflict-free b128 row reads)
#define SWV(r,c) (((r)<<6) + (((((c)>>3) ^ ((r)&7))<<3) | ((c)&7)))
#define SW(r,c)  SWV(r,c)
#define MFMA(a,b,c) __builtin_amdgcn_mfma_f32_16x16x32_bf16(a,b,c,0,0,0)

__device__ __forceinline__ short f2bf(float f) {
    unsigned u = __float_as_uint(f);
    u += 0x7fffu + ((u >> 16) & 1u);   // RNE; inputs never NaN/inf
    return (short)(u >> 16);
}
__device__ __forceinline__ float bf2f(short v) {
    return __uint_as_float(((unsigned)(unsigned short)v) << 16);
}

// ---------------- SE: global average pool per (b,c) ----------------
__global__ void k_pool(const float* __restrict__ high, float* __restrict__ pooled) {
    int bc = blockIdx.x;
    const float* src = high + (size_t)bc * (NHW*NHW);
    float s = 0.f;
    for (int i = threadIdx.x; i < NHW*NHW; i += 256) s += src[i];
    for (int off = 32; off > 0; off >>= 1) s += __shfl_down(s, off);
    __shared__ float red[4];
    int lane = threadIdx.x & 63, wv = threadIdx.x >> 6;
    if (lane == 0) red[wv] = s;
    __syncthreads();
    if (threadIdx.x == 0)
        pooled[bc] = (red[0] + red[1] + red[2] + red[3]) * (1.f / (NHW*NHW));
}

// ---------------- SE: gate s[b,c] ----------------
__global__ void k_gate(const float* __restrict__ pooled,
                       const float* __restrict__ w10, const float* __restrict__ w20,
                       const float* __restrict__ w11, const float* __restrict__ w21,
                       const float* __restrict__ w12, const float* __restrict__ w22,
                       float* __restrict__ sgate) {
    __shared__ float pl[256];
    int t = threadIdx.x;
    pl[t] = pooled[t];
    __syncthreads();
    int b = t >> 6, c = t & 63;
    const float* w1; const float* w2; int o0, gc;
    if (c < 22)      { w1 = w10; w2 = w20; o0 = 0;  gc = 22; }
    else if (c < 43) { w1 = w11; w2 = w21; o0 = 22; gc = 21; }
    else             { w1 = w12; w2 = w22; o0 = 43; gc = 21; }
    float a = 0.f;
    for (int k = 0; k < gc; ++k) a += pl[b*64 + o0 + k] * w1[k];
    a = fmaxf(a, 0.f);
    float z = a * w2[c - o0];
    sgate[t] = 1.f / (1.f + __expf(-z));
}

// ---------------- prep: weights fp32 -> bf16 ----------------
__global__ void k_prepw(const float* __restrict__ w0, const float* __restrict__ w1,
                        const float* __restrict__ w2, const float* __restrict__ w3,
                        const float* __restrict__ w4, const float* __restrict__ w5,
                        const float* __restrict__ w6, const float* __restrict__ w7,
                        short* __restrict__ wb) {
    int mat = blockIdx.x >> 4;                       // 16 blocks per 4096-elem matrix
    int j = ((blockIdx.x & 15) << 8) + threadIdx.x;
    const float* src = mat == 0 ? w0 : mat == 1 ? w1 : mat == 2 ? w2 : mat == 3 ? w3 :
                       mat == 4 ? w4 : mat == 5 ? w5 : mat == 6 ? w6 : w7;
    wb[mat*4096 + j] = f2bf(src[j]);
}

// ---------------- prep: X fp32 [b][c][h][w] -> bf16 channel-last [b][h][w][c] ----------------
__global__ __launch_bounds__(256) void k_prepx(const float* __restrict__ src,
                                               const float* __restrict__ gate,
                                               short* __restrict__ dst) {
    __shared__ float T[64*129];
    int b = blockIdx.x >> 7, h = blockIdx.x & 127;
    int t = threadIdx.x;
    for (int e = t; e < 64*128; e += 256) {
        int c = e >> 7, ww = e & 127;
        float v = src[(((size_t)b*64 + c)*NHW + h)*NHW + ww];
        if (gate) v *= gate[b*64 + c];
        T[c*129 + ww] = v;
    }
    __syncthreads();
    for (int e = t; e < 2048; e += 256) {
        int ww = e >> 4, c4 = (e & 15) << 2;
        short4v s;
        #pragma unroll
        for (int i = 0; i < 4; ++i) s[i] = f2bf(T[(c4 + i)*129 + ww]);
        *(short4v*)(dst + (((size_t)b*NHW + h)*NHW + ww)*64 + c4) = s;
    }
}

// X fragment from channel-last bf16: pixel np of window, 8 channels at kf*32+quad*8.
// Serves A-frags (row np = l16) and B-frags (col np = l16) identically.
__device__ __forceinline__ short8 xfrag(const short* __restrict__ X, int b,
                                        int row0, int col0, int np, int kf, int quad) {
    int rr = row0 + (np >> 3), cc = col0 + (np & 7);
    return *(const short8*)(X + (((size_t)b*NHW + rr)*NHW + cc)*64 + kf*32 + quad*8);
}
// Weight fragment (bf16 row-major W[o][c]); row = o (A-frag row / B-frag col = l16-mapped)
__device__ __forceinline__ short8 wfrag(const short* __restrict__ W, int row, int kf, int quad) {
    return *(const short8*)(W + row*64 + kf*32 + quad*8);
}

// windows covering coordinate x (ws=8, stride 4)
__device__ __forceinline__ float rowcount(int x) {
    int lo = (x >= 7) ? ((x - 4) >> 2) : 0;
    int hi = x >> 2; hi = hi > 30 ? 30 : hi;
    return (float)(hi - lo + 1);
}

// ---------------- windowed cross attention, one pass, wave = head ----------------
// MODE 0: per-window O (bf16) -> scr [b][l][np][c]
// MODE 1: atomicAdd into fold accumulator   MODE 2: plain store (parity (0,0))
template<int MODE>
__global__ __launch_bounds__(256, 4) void k_attn(
    const short* __restrict__ Xq, const short* __restrict__ Xkv,
    const short* __restrict__ Wq, const short* __restrict__ Wk, const short* __restrict__ Wv,
    short* __restrict__ scr, float* __restrict__ outp,
    int pr, int pc, int nr, int nc) {
    // per-wave LDS: QT 64x16 stride24 (1536) | KT (1536) | VT 16x64 swz (1024) | PT 16x64 swz (1024)
    __shared__ __align__(16) short SH[5120*4];
    int bidx = blockIdx.x, nrc = nr * nc;
    int b = bidx / nrc, rem = bidx - b*nrc;
    int wr = rem / nc, wc = rem - (rem/nc)*nc;
    if (MODE != 0) { wr = pr + 2*wr; wc = pc + 2*wc; }
    int l = wr*NWIN + wc, row0 = wr*4, col0 = wc*4;
    int t = threadIdx.x, w = t >> 6, ln = t & 63, l16 = ln & 15, quad = ln >> 4;
    int h = w;
    short* QT = SH + w*5120;
    short* KT = QT + 1536;
    short* VT = QT + 3072;
    short* PT = QT + 4096;
    int wrow = 16*h + l16;
    short8 z = {0,0,0,0,0,0,0,0};

    short8 wq0 = wfrag(Wq, wrow, 0, quad), wq1 = wfrag(Wq, wrow, 1, quad);
    short8 wk0 = wfrag(Wk, wrow, 0, quad), wk1 = wfrag(Wk, wrow, 1, quad);
    short8 wv0 = wfrag(Wv, wrow, 0, quad), wv1 = wfrag(Wv, wrow, 1, quad);

    // Xkv frags, shared by K^T and V computation
    short8 xk[4][2];
    #pragma unroll
    for (int nt = 0; nt < 4; ++nt) {
        xk[nt][0] = xfrag(Xkv, b, row0, col0, nt*16 + l16, 0, quad);
        xk[nt][1] = xfrag(Xkv, b, row0, col0, nt*16 + l16, 1, quad);
    }
    // Q^T slice [np][d16]
    #pragma unroll
    for (int nt = 0; nt < 4; ++nt) {
        short8 x0 = xfrag(Xq, b, row0, col0, nt*16 + l16, 0, quad);
        short8 x1 = xfrag(Xq, b, row0, col0, nt*16 + l16, 1, quad);
        f4 acc = {0.f,0.f,0.f,0.f};
        acc = MFMA(x0, wq0, acc); acc = MFMA(x1, wq1, acc);
        #pragma unroll
        for (int r = 0; r < 4; ++r) QT[(nt*16 + quad*4 + r)*24 + l16] = f2bf(acc[r]);
    }
    // K^T slice [m][d16]
    #pragma unroll
    for (int nt = 0; nt < 4; ++nt) {
        f4 acc = {0.f,0.f,0.f,0.f};
        acc = MFMA(xk[nt][0], wk0, acc); acc = MFMA(xk[nt][1], wk1, acc);
        #pragma unroll
        for (int r = 0; r < 4; ++r) KT[(nt*16 + quad*4 + r)*24 + l16] = f2bf(acc[r]);
    }
    // V slice [d16][np]
    #pragma unroll
    for (int nt = 0; nt < 4; ++nt) {
        f4 acc = {0.f,0.f,0.f,0.f};
        acc = MFMA(wv0, xk[nt][0], acc); acc = MFMA(wv1, xk[nt][1], acc);
        #pragma unroll
        for (int r = 0; r < 4; ++r) VT[SWV(quad*4 + r, nt*16 + l16)] = f2bf(acc[r]);
    }

    short8 kb[4];
    #pragma unroll
    for (int mt = 0; mt < 4; ++mt)
        kb[mt] = (quad < 2) ? *(const short8*)(KT + (mt*16 + l16)*24 + quad*8) : z;
    short8 va0 = *(const short8*)(VT + SWV(l16, quad*8));
    short8 va1 = *(const short8*)(VT + SWV(l16, 32 + quad*8));

    #pragma unroll
    for (int ntl = 0; ntl < 4; ++ntl) {
        short8 qa = (quad < 2) ? *(const short8*)(QT + (ntl*16 + l16)*24 + quad*8) : z;
        f4 s[4];
        #pragma unroll
        for (int mt = 0; mt < 4; ++mt) {
            f4 acc = {0.f,0.f,0.f,0.f};
            s[mt] = MFMA(qa, kb[mt], acc);
        }
        // softmax over m (4 mt regs x 16 lanes), rows n = ntl*16 + quad*4 + r
        f4 mx = s[0];
        #pragma unroll
        for (int mt = 1; mt < 4; ++mt)
            #pragma unroll
            for (int r = 0; r < 4; ++r) mx[r] = fmaxf(mx[r], s[mt][r]);
        #pragma unroll
        for (int d = 1; d < 16; d <<= 1)
            #pragma unroll
            for (int r = 0; r < 4; ++r) mx[r] = fmaxf(mx[r], __shfl_xor(mx[r], d));
        f4 sum = {0.f,0.f,0.f,0.f};
        #pragma unroll
        for (int mt = 0; mt < 4; ++mt)
            #pragma unroll
            for (int r = 0; r < 4; ++r) {
                float e = __expf((s[mt][r] - mx[r]) * 0.25f);
                s[mt][r] = e; sum[r] += e;
            }
        #pragma unroll
        for (int d = 1; d < 16; d <<= 1)
            #pragma unroll
            for (int r = 0; r < 4; ++r) sum[r] += __shfl_xor(sum[r], d);
        #pragma unroll
        for (int r = 0; r < 4; ++r) sum[r] = 1.f / sum[r];
        #pragma unroll
        for (int mt = 0; mt < 4; ++mt)
            #pragma unroll
            for (int r = 0; r < 4; ++r)
                PT[SWV(quad*4 + r, mt*16 + l16)] = f2bf(s[mt][r] * sum[r]);
        // O tile: O[d][np] = V_h P^T, np block = ntl
        f4 o = {0.f,0.f,0.f,0.f};
        o = MFMA(va0, *(const short8*)(PT + SWV(l16, quad*8)), o);
        o = MFMA(va1, *(const short8*)(PT + SWV(l16, 32 + quad*8)), o);
        int np = ntl*16 + l16;
        if (MODE == 0) {
            short4v sv;
            #pragma unroll
            for (int r = 0; r < 4; ++r) sv[r] = f2bf(o[r]);
            *(short4v*)(scr + (((size_t)(b*NL + l)*64 + np)*64) + 16*h + quad*4) = sv;
        } else {
            int rr = row0 + (np >> 3), cc = col0 + (np & 7);
            #pragma unroll
            for (int r = 0; r < 4; ++r) {
                size_t gi = (((size_t)(b*64 + 16*h + quad*4 + r))*NHW + rr)*NHW + cc;
                if (MODE == 2) outp[gi] = o[r];
                else atomicAdd(&outp[gi], o[r]);
            }
        }
    }
}

// ---------------- fold(gather) + mask + 1x1 proj (bf16 W) + residual ----------------
__global__ __launch_bounds__(256) void k_gather(
    const short* __restrict__ scr, const float* __restrict__ resid,
    const short* __restrict__ wproj, float* __restrict__ outp) {
    __shared__ __align__(16) short G[8192];    // G[p][c], swizzled
    int bidx = blockIdx.x; int b = bidx >> 7, hh = bidx & 127;
    int t = threadIdx.x;
    int p = t >> 1, c0 = (t & 1) * 32;
    float g[32];
    #pragma unroll
    for (int k = 0; k < 32; ++k) g[k] = 0.f;
    int wrlo = (hh >= 8) ? ((hh - 4) >> 2) : 0;
    int wrhi = hh >> 2; if (wrhi > 30) wrhi = 30;
    int wclo = (p >= 8) ? ((p - 4) >> 2) : 0;
    int wchi = p >> 2; if (wchi > 30) wchi = 30;
    for (int wr = wrlo; wr <= wrhi; ++wr)
        for (int wc = wclo; wc <= wchi; ++wc) {
            int np = (hh - 4*wr)*8 + (p - 4*wc);
            const short* src = scr + (((size_t)(b*NL + wr*NWIN + wc)*64 + np)*64) + c0;
            #pragma unroll
            for (int k4 = 0; k4 < 4; ++k4) {
                short8 v = *(const short8*)(src + k4*8);
                #pragma unroll
                for (int j = 0; j < 8; ++j) g[k4*8 + j] += bf2f(v[j]);
            }
        }
    float inv = 1.f / (rowcount(hh) * rowcount(p));
    #pragma unroll
    for (int k4 = 0; k4 < 4; ++k4) {
        short8 v;
        #pragma unroll
        for (int j = 0; j < 8; ++j) v[j] = f2bf(g[k4*8 + j] * inv);
        *(short8*)(G + SW(p, c0 + k4*8)) = v;
    }
    __syncthreads();
    int w = t >> 6, ln = t & 63, l16 = ln & 15, quad = ln >> 4;
    short8 wa0 = wfrag(wproj, 16*w + l16, 0, quad);
    short8 wa1 = wfrag(wproj, 16*w + l16, 1, quad);
    #pragma unroll
    for (int pt = 0; pt < 8; ++pt) {
        f4 acc = {0.f,0.f,0.f,0.f};
        acc = MFMA(wa0, *(const short8*)(G + SW(pt*16 + l16, quad*8)), acc);
        acc = MFMA(wa1, *(const short8*)(G + SW(pt*16 + l16, 32 + quad*8)), acc);
        #pragma unroll
        for (int r = 0; r < 4; ++r) {
            size_t gi = (((size_t)(b*64 + 16*w + quad*4 + r))*NHW + hh)*NHW + pt*16 + l16;
            outp[gi] = resid[gi] + acc[r];
        }
    }
}

// ---------------- fallback: mask + 1x1 proj + residual (fp32, in place) ----------------
__global__ __launch_bounds__(256) void k_final(const float* __restrict__ resid,
                                               const float* __restrict__ wproj,
                                               float* __restrict__ acc) {
    int blk = blockIdx.x;
    int b = blk >> 8, hrow = (blk >> 1) & 127, w0 = (blk & 1) << 6;
    __shared__ float X[4096];
    int t = threadIdx.x;
    float rh = rowcount(hrow);
    for (int e = t; e < 4096; e += 256) {
        int c = e >> 6, p = e & 63;
        float m = rh * rowcount(w0 + p);
        X[e] = acc[(((size_t)b*64 + c)*NHW + hrow)*NHW + w0 + p] * (1.f / m);
    }
    __syncthreads();
    int p = t & 63, ob = (t >> 6) << 4;
    float xc[64];
    #pragma unroll
    for (int k = 0; k < 64; ++k) xc[k] = X[k*64 + p];
    for (int j = 0; j < 16; ++j) {
        const float* wr2 = wproj + (ob + j)*64;
        float a = 0.f;
        #pragma unroll
        for (int k = 0; k < 64; ++k) a = fmaf(wr2[k], xc[k], a);
        size_t gi = (((size_t)b*64 + ob + j)*NHW + hrow)*NHW + w0 + p;
        acc[gi] = resid[gi] + a;
    }
}

extern "C" void kernel_launch(void* const* d_in, const int* in_sizes, int n_in,
                              void* d_out, int out_size, void* d_ws, size_t ws_size,
                              hipStream_t stream) {
    const float* low  = (const float*)d_in[0];
    const float* high = (const float*)d_in[1];
    float* out = (float*)d_out;
    float* pooled = (float*)d_ws;                       // 256 f
    float* sgate  = pooled + 256;                       // 256 f
    short* wb  = (short*)((char*)d_ws + 4096);          // 8 x 4096 bf16
    short* xl  = (short*)((char*)d_ws + 4096 + 65536);  // [b][h][w][c] bf16
    short* xh  = xl + (size_t)NB*NHW*NHW*64;
    short* scr = xh + (size_t)NB*NHW*NHW*64;            // one direction's O
    size_t need = 4096 + 65536 + 2*(size_t)NB*NHW*NHW*64*2 + (size_t)NB*NL*64*64*2;
    size_t plane = (size_t)NB*64*NHW*NHW;

    k_pool<<<dim3(NB*64), dim3(256), 0, stream>>>(high, pooled);
    k_gate<<<dim3(1), dim3(256), 0, stream>>>(pooled,
        (const float*)d_in[10], (const float*)d_in[11],
        (const float*)d_in[12], (const float*)d_in[13],
        (const float*)d_in[14], (const float*)d_in[15], sgate);
    k_prepw<<<dim3(128), dim3(256), 0, stream>>>(
        (const float*)d_in[2], (const float*)d_in[3], (const float*)d_in[4],
        (const float*)d_in[5], (const float*)d_in[6], (const float*)d_in[7],
        (const float*)d_in[8], (const float*)d_in[9], wb);
    k_prepx<<<dim3(NB*NHW), dim3(256), 0, stream>>>(low,  nullptr, xl);
    k_prepx<<<dim3(NB*NHW), dim3(256), 0, stream>>>(high, sgate,   xh);

    const short* Wql = wb;            const short* Wkh = wb + 4096;
    const short* Wvh = wb + 2*4096;   const short* Wqh = wb + 3*4096;
    const short* Wkl = wb + 4*4096;   const short* Wvl = wb + 5*4096;
    const short* Wpl = wb + 6*4096;   const short* Wph = wb + 7*4096;

    if (ws_size >= need) {
        // pass 0: Q=low, K/V=high_gated -> out_l
        k_attn<0><<<dim3(NB*NL), dim3(256), 0, stream>>>(xl, xh, Wql, Wkh, Wvh,
            scr, nullptr, 0, 0, NB == 0 ? 0 : NWIN, NWIN);
        k_gather<<<dim3(NB*NHW), dim3(256), 0, stream>>>(scr, low, Wpl, out);
        // pass 1: Q=high_gated, K/V=low -> out_h
        k_attn<0><<<dim3(NB*NL), dim3(256), 0, stream>>>(xh, xl, Wqh, Wkl, Wvl,
            scr, nullptr, 0, 0, NWIN, NWIN);
        k_gather<<<dim3(NB*NHW), dim3(256), 0, stream>>>(scr, high, Wph, out + plane);
    } else {
        // parity fold: (0,0) windows tile the plane -> plain store; rest atomicAdd
        for (int pass = 0; pass < 2; ++pass) {
            const short* Xq  = pass ? xh : xl;
            const short* Xkv = pass ? xl : xh;
            const short* Wq  = pass ? Wqh : Wql;
            const short* Wk  = pass ? Wkl : Wkh;
            const short* Wv  = pass ? Wvl : Wvh;
            float* op = out + (size_t)pass * plane;
            k_attn<2><<<dim3(NB*16*16), dim3(256), 0, stream>>>(Xq, Xkv, Wq, Wk, Wv,
                nullptr, op, 0, 0, 16, 16);
            k_attn<1><<<dim3(NB*16*15), dim3(256), 0, stream>>>(Xq, Xkv, Wq, Wk, Wv,
                nullptr, op, 0, 1, 16, 15);
            k_attn<1><<<dim3(NB*15*16), dim3(256), 0, stream>>>(Xq, Xkv, Wq, Wk, Wv,
                nullptr, op, 1, 0, 15, 16);
            k_attn<1><<<dim3(NB*15*15), dim3(256), 0, stream>>>(Xq, Xkv, Wq, Wk, Wv,
                nullptr, op, 1, 1, 15, 15);
        }
        k_final<<<dim3(NB*NHW*2), dim3(256), 0, stream>>>(low,  (const float*)d_in[8], out);
        k_final<<<dim3(NB*NHW*2), dim3(256), 0, stream>>>(high, (const float*)d_in[9], out + plane);
    }
}

// Round 5
// 247.636 us; speedup vs baseline: 4.3056x; 1.1466x over previous
//
#include <hip/hip_runtime.h>

typedef short short8 __attribute__((ext_vector_type(8)));
typedef short short4v __attribute__((ext_vector_type(4)));
typedef float f4 __attribute__((ext_vector_type(4)));

#define NB 4
#define NHW 128
#define NPX (NHW*NHW)
#define NWIN 31
#define NL (NWIN*NWIN)
// 64-wide row, 8-col-block XOR swizzle (conflict-free b128 row reads)
#define SWV(r,c) (((r)<<6) + (((((c)>>3) ^ ((r)&7))<<3) | ((c)&7)))
#define MFMA(a,b,c) __builtin_amdgcn_mfma_f32_16x16x32_bf16(a,b,c,0,0,0)

__device__ __forceinline__ short f2bf(float f) {
    unsigned u = __float_as_uint(f);
    u += 0x7fffu + ((u >> 16) & 1u);   // RNE; inputs never NaN/inf
    return (short)(u >> 16);
}
__device__ __forceinline__ float bf2f(short v) {
    return __uint_as_float(((unsigned)(unsigned short)v) << 16);
}

// ---------------- SE: global average pool per (b,c) ----------------
__global__ void k_pool(const float* __restrict__ high, float* __restrict__ pooled) {
    int bc = blockIdx.x;
    const float* src = high + (size_t)bc * NPX;
    float s = 0.f;
    for (int i = threadIdx.x; i < NPX; i += 256) s += src[i];
    for (int off = 32; off > 0; off >>= 1) s += __shfl_down(s, off);
    __shared__ float red[4];
    int lane = threadIdx.x & 63, wv = threadIdx.x >> 6;
    if (lane == 0) red[wv] = s;
    __syncthreads();
    if (threadIdx.x == 0)
        pooled[bc] = (red[0] + red[1] + red[2] + red[3]) * (1.f / NPX);
}

// ---------------- SE: gate s[b,c] ----------------
__global__ void k_gate(const float* __restrict__ pooled,
                       const float* __restrict__ w10, const float* __restrict__ w20,
                       const float* __restrict__ w11, const float* __restrict__ w21,
                       const float* __restrict__ w12, const float* __restrict__ w22,
                       float* __restrict__ sgate) {
    __shared__ float pl[256];
    int t = threadIdx.x;
    pl[t] = pooled[t];
    __syncthreads();
    int b = t >> 6, c = t & 63;
    const float* w1; const float* w2; int o0, gc;
    if (c < 22)      { w1 = w10; w2 = w20; o0 = 0;  gc = 22; }
    else if (c < 43) { w1 = w11; w2 = w21; o0 = 22; gc = 21; }
    else             { w1 = w12; w2 = w22; o0 = 43; gc = 21; }
    float a = 0.f;
    for (int k = 0; k < gc; ++k) a += pl[b*64 + o0 + k] * w1[k];
    a = fmaxf(a, 0.f);
    float z = a * w2[c - o0];
    sgate[t] = 1.f / (1.f + __expf(-z));
}

// windows covering coordinate x (ws=8, stride 4): [lo,hi]
__device__ __forceinline__ void wrange(int x, int& lo, int& hi) {
    lo = (x >= 7) ? ((x - 4) >> 2) : 0;
    hi = x >> 2; if (hi > 30) hi = 30;
}

// ---------------- per-pixel projections (GEMM), fused fp32->bf16 ----------------
// One block per (b, image row). Computes Y = W X for up to 3 weight matrices.
// EMIT bit0: Q -> ch-last [b][px][64]; bit1: K -> ch-last; bit2: V -> planar [b][64][px]
template<int EMIT>
__global__ __launch_bounds__(256, 4) void k_proj(
    const float* __restrict__ src, const float* __restrict__ gate,
    const float* __restrict__ Wq, const float* __restrict__ Wk, const float* __restrict__ Wv,
    short* __restrict__ Qp, short* __restrict__ Kp, short* __restrict__ Vp) {
    __shared__ float T[64*129];                 // X row tile, [c][px] pitch 129
    int b = blockIdx.x >> 7, row = blockIdx.x & 127;
    int t = threadIdx.x;
    const float* sp = src + (size_t)b*64*NPX + row*NHW;
    #pragma unroll
    for (int i = 0; i < 8; ++i) {
        int f = t + i*256;                      // 2048 float4 chunks
        int c = f >> 5, p4 = (f & 31) << 2;
        float4 v = *(const float4*)(sp + (size_t)c*NPX + p4);
        float g = gate ? gate[b*64 + c] : 1.f;
        T[c*129 + p4 + 0] = v.x * g;
        T[c*129 + p4 + 1] = v.y * g;
        T[c*129 + p4 + 2] = v.z * g;
        T[c*129 + p4 + 3] = v.w * g;
    }
    __syncthreads();
    int w = t >> 6, ln = t & 63, l16 = ln & 15, quad = ln >> 4;
    int orow = 16*w + l16;
    // weight A-frags, converted inline from fp32
    short8 wq[2], wk[2], wv[2];
    #pragma unroll
    for (int kf = 0; kf < 2; ++kf) {
        if (EMIT & 1) {
            const float* p = Wq + orow*64 + kf*32 + quad*8;
            #pragma unroll
            for (int j = 0; j < 8; ++j) wq[kf][j] = f2bf(p[j]);
        }
        if (EMIT & 2) {
            const float* p = Wk + orow*64 + kf*32 + quad*8;
            #pragma unroll
            for (int j = 0; j < 8; ++j) wk[kf][j] = f2bf(p[j]);
        }
        if (EMIT & 4) {
            const float* p = Wv + orow*64 + kf*32 + quad*8;
            #pragma unroll
            for (int j = 0; j < 8; ++j) wv[kf][j] = f2bf(p[j]);
        }
    }
    #pragma unroll
    for (int nt = 0; nt < 8; ++nt) {
        int px = nt*16 + l16;
        short8 xb[2];
        #pragma unroll
        for (int kf = 0; kf < 2; ++kf) {
            const float* p = T + (kf*32 + quad*8)*129 + px;
            #pragma unroll
            for (int j = 0; j < 8; ++j) xb[kf][j] = f2bf(p[j*129]);
        }
        size_t clbase = ((size_t)b*NPX + row*NHW + px)*64 + 16*w + quad*4;
        if (EMIT & 1) {
            f4 acc = {0.f,0.f,0.f,0.f};
            acc = MFMA(wq[0], xb[0], acc); acc = MFMA(wq[1], xb[1], acc);
            short4v sv;
            #pragma unroll
            for (int r = 0; r < 4; ++r) sv[r] = f2bf(acc[r]);
            *(short4v*)(Qp + clbase) = sv;
        }
        if (EMIT & 2) {
            f4 acc = {0.f,0.f,0.f,0.f};
            acc = MFMA(wk[0], xb[0], acc); acc = MFMA(wk[1], xb[1], acc);
            short4v sv;
            #pragma unroll
            for (int r = 0; r < 4; ++r) sv[r] = f2bf(acc[r]);
            *(short4v*)(Kp + clbase) = sv;
        }
        if (EMIT & 4) {
            f4 acc = {0.f,0.f,0.f,0.f};
            acc = MFMA(wv[0], xb[0], acc); acc = MFMA(wv[1], xb[1], acc);
            #pragma unroll
            for (int r = 0; r < 4; ++r)
                Vp[((size_t)(b*64 + 16*w + quad*4 + r))*NPX + row*NHW + px] = f2bf(acc[r]);
        }
    }
}

// ---------------- windowed cross attention (S, softmax, PV only) ----------------
// scr: parity planes [4][nb][px][64] bf16; same-parity windows tile the plane.
__global__ __launch_bounds__(256, 4) void k_attn(
    const short* __restrict__ Qp, const short* __restrict__ Kp,
    const short* __restrict__ Vp, short* __restrict__ scr, int nb) {
    __shared__ __align__(16) short Pb[4][1024];   // per-wave P [16 n][64 m], swizzled
    int bidx = blockIdx.x;
    int b = bidx / NL, l = bidx - b*NL;
    int wr = l / NWIN, wc = l - (l/NWIN)*NWIN;
    int row0 = wr*4, col0 = wc*4;
    int parity = (wr & 1)*2 + (wc & 1);
    int t = threadIdx.x, w = t >> 6, ln = t & 63, l16 = ln & 15, quad = ln >> 4;
    int h = w;
    short* PT = Pb[w];
    short8 z = {0,0,0,0,0,0,0,0};

    // K B-frags: B[k=d][col=m], m = mt*16+l16, d = quad*8+j (quad<2)
    short8 kb[4];
    #pragma unroll
    for (int mt = 0; mt < 4; ++mt) {
        int m = mt*16 + l16;
        int px = (row0 + (m >> 3))*NHW + col0 + (m & 7);
        kb[mt] = (quad < 2) ? *(const short8*)(Kp + ((size_t)b*NPX + px)*64 + h*16 + quad*8) : z;
    }
    // V A-frags: A[row=d=l16][k=m]; planar V: row rr, 8 consecutive cols
    short8 va0, va1;
    {
        const short* vb = Vp + ((size_t)(b*64 + h*16 + l16))*NPX;
        const short* p0 = vb + (row0 + quad)*NHW + col0;
        const short* p1 = vb + (row0 + 4 + quad)*NHW + col0;
        short4v a = *(const short4v*)p0, bq = *(const short4v*)(p0 + 4);
        short4v c = *(const short4v*)p1, d = *(const short4v*)(p1 + 4);
        #pragma unroll
        for (int j = 0; j < 4; ++j) { va0[j] = a[j]; va0[4+j] = bq[j]; va1[j] = c[j]; va1[4+j] = d[j]; }
    }

    #pragma unroll
    for (int ntl = 0; ntl < 4; ++ntl) {
        int n = ntl*16 + l16;
        int px = (row0 + (n >> 3))*NHW + col0 + (n & 7);
        short8 qa = (quad < 2) ? *(const short8*)(Qp + ((size_t)b*NPX + px)*64 + h*16 + quad*8) : z;
        f4 s[4];
        #pragma unroll
        for (int mt = 0; mt < 4; ++mt) {
            f4 acc = {0.f,0.f,0.f,0.f};
            s[mt] = MFMA(qa, kb[mt], acc);
        }
        // softmax over m (4 regs x 16 lanes); no max pass (|S|*0.25 << 30), clamp for safety
        f4 sum = {0.f,0.f,0.f,0.f};
        #pragma unroll
        for (int mt = 0; mt < 4; ++mt)
            #pragma unroll
            for (int r = 0; r < 4; ++r) {
                float e = __expf(fminf(s[mt][r]*0.25f, 30.f));
                s[mt][r] = e; sum[r] += e;
            }
        #pragma unroll
        for (int d = 1; d < 16; d <<= 1)
            #pragma unroll
            for (int r = 0; r < 4; ++r) sum[r] += __shfl_xor(sum[r], d);
        #pragma unroll
        for (int r = 0; r < 4; ++r) sum[r] = 1.f / sum[r];
        #pragma unroll
        for (int mt = 0; mt < 4; ++mt)
            #pragma unroll
            for (int r = 0; r < 4; ++r)
                PT[SWV(quad*4 + r, mt*16 + l16)] = f2bf(s[mt][r] * sum[r]);
        // O[d][n] = V_h P^T  (in-wave LDS RAW, waitcnt-ordered; no barrier needed)
        f4 o = {0.f,0.f,0.f,0.f};
        o = MFMA(va0, *(const short8*)(PT + SWV(l16, quad*8)), o);
        o = MFMA(va1, *(const short8*)(PT + SWV(l16, 32 + quad*8)), o);
        short4v sv;
        #pragma unroll
        for (int r = 0; r < 4; ++r) sv[r] = f2bf(o[r]);
        *(short4v*)(scr + (((size_t)(parity*nb + b))*NPX + px)*64 + h*16 + quad*4) = sv;
    }
}

// ---------------- fold from parity planes + mask + 1x1 proj + residual ----------------
__global__ __launch_bounds__(256, 4) void k_gather(
    const short* __restrict__ scr, const float* __restrict__ resid,
    const float* __restrict__ wproj, float* __restrict__ outp, int nb) {
    __shared__ __align__(16) short G[8192];       // [px 0..127][64 ch], swizzled
    int bidx = blockIdx.x, b = bidx >> 7, hh = bidx & 127;
    int t = threadIdx.x;
    int p = t >> 1, c0 = (t & 1)*32;
    int rlo, rhi, clo, chi;
    wrange(hh, rlo, rhi); wrange(p, clo, chi);
    float vr[2], vc[2];
    vr[0] = (rhi > rlo || (rlo & 1) == 0) ? 1.f : 0.f;
    vr[1] = (rhi > rlo || (rlo & 1) == 1) ? 1.f : 0.f;
    vc[0] = (chi > clo || (clo & 1) == 0) ? 1.f : 0.f;
    vc[1] = (chi > clo || (clo & 1) == 1) ? 1.f : 0.f;
    float g[32];
    #pragma unroll
    for (int k = 0; k < 32; ++k) g[k] = 0.f;
    #pragma unroll
    for (int par = 0; par < 4; ++par) {
        float wgt = vr[par >> 1] * vc[par & 1];
        const short* srcp = scr + (((size_t)(par*nb + b))*NPX + hh*NHW + p)*64 + c0;
        #pragma unroll
        for (int k4 = 0; k4 < 4; ++k4) {
            short8 v = *(const short8*)(srcp + k4*8);
            #pragma unroll
            for (int j = 0; j < 8; ++j) g[k4*8 + j] += wgt * bf2f(v[j]);
        }
    }
    float inv = 1.f / ((float)(rhi - rlo + 1) * (float)(chi - clo + 1));
    #pragma unroll
    for (int k4 = 0; k4 < 4; ++k4) {
        short8 v;
        #pragma unroll
        for (int j = 0; j < 8; ++j) v[j] = f2bf(g[k4*8 + j] * inv);
        *(short8*)(G + SWV(p, c0 + k4*8)) = v;
    }
    __syncthreads();
    int w = t >> 6, ln = t & 63, l16 = ln & 15, quad = ln >> 4;
    short8 wa0, wa1;
    {
        const float* p0 = wproj + (16*w + l16)*64 + quad*8;
        #pragma unroll
        for (int j = 0; j < 8; ++j) { wa0[j] = f2bf(p0[j]); wa1[j] = f2bf(p0[32 + j]); }
    }
    #pragma unroll
    for (int pt = 0; pt < 8; ++pt) {
        f4 acc = {0.f,0.f,0.f,0.f};
        acc = MFMA(wa0, *(const short8*)(G + SWV(pt*16 + l16, quad*8)), acc);
        acc = MFMA(wa1, *(const short8*)(G + SWV(pt*16 + l16, 32 + quad*8)), acc);
        #pragma unroll
        for (int r = 0; r < 4; ++r) {
            size_t gi = (((size_t)(b*64 + 16*w + quad*4 + r))*NHW + hh)*NHW + pt*16 + l16;
            outp[gi] = resid[gi] + acc[r];
        }
    }
}

extern "C" void kernel_launch(void* const* d_in, const int* in_sizes, int n_in,
                              void* d_out, int out_size, void* d_ws, size_t ws_size,
                              hipStream_t stream) {
    const float* low  = (const float*)d_in[0];
    const float* high = (const float*)d_in[1];
    const float* w_ql = (const float*)d_in[2];
    const float* w_kh = (const float*)d_in[3];
    const float* w_vh = (const float*)d_in[4];
    const float* w_qh = (const float*)d_in[5];
    const float* w_kl = (const float*)d_in[6];
    const float* w_vl = (const float*)d_in[7];
    const float* w_pl = (const float*)d_in[8];
    const float* w_ph = (const float*)d_in[9];
    float* out = (float*)d_out;
    float* pooled = (float*)d_ws;
    float* sgate  = pooled + 256;
    short* base = (short*)((char*)d_ws + 2048);
    const size_t PL = (size_t)NB * NPX * 64;            // elems per bf16 plane (8.39 MB)
    const size_t plane_f = (size_t)NB * 64 * NPX;       // fp32 out plane elems
    size_t need_full = 2048 + (6*PL + 4*PL) * sizeof(short);          // 6 planes + full scr
    size_t scr_elems_per_b = 4 * (size_t)NPX * 64;

    k_pool<<<dim3(NB*64), dim3(256), 0, stream>>>(high, pooled);
    k_gate<<<dim3(1), dim3(256), 0, stream>>>(pooled,
        (const float*)d_in[10], (const float*)d_in[11],
        (const float*)d_in[12], (const float*)d_in[13],
        (const float*)d_in[14], (const float*)d_in[15], sgate);

    if (ws_size >= need_full) {
        short* QL = base;        short* KL = base + PL;   short* VL = base + 2*PL;
        short* QH = base + 3*PL; short* KH = base + 4*PL; short* VH = base + 5*PL;
        short* scr = base + 6*PL;
        k_proj<7><<<dim3(NB*NHW), dim3(256), 0, stream>>>(low,  nullptr, w_ql, w_kl, w_vl, QL, KL, VL);
        k_proj<7><<<dim3(NB*NHW), dim3(256), 0, stream>>>(high, sgate,   w_qh, w_kh, w_vh, QH, KH, VH);
        k_attn<<<dim3(NB*NL), dim3(256), 0, stream>>>(QL, KH, VH, scr, NB);
        k_gather<<<dim3(NB*NHW), dim3(256), 0, stream>>>(scr, low, w_pl, out, NB);
        k_attn<<<dim3(NB*NL), dim3(256), 0, stream>>>(QH, KL, VL, scr, NB);
        k_gather<<<dim3(NB*NHW), dim3(256), 0, stream>>>(scr, high, w_ph, out + plane_f, NB);
    } else {
        // trio mode: 3 plane slots + batch-chunked scr
        short* P0 = base; short* P1 = base + PL; short* P2 = base + 2*PL;
        short* scr = base + 3*PL;
        int nbc = 0;
        for (int n = NB; n >= 1; n >>= 1)
            if (ws_size >= 2048 + (3*PL + n*scr_elems_per_b)*sizeof(short)) { nbc = n; break; }
        if (nbc == 0) nbc = 1;
        for (int pass = 0; pass < 2; ++pass) {
            const float* qsrc = pass ? high : low;
            const float* ksrc = pass ? low  : high;
            const float* qg   = pass ? sgate : nullptr;
            const float* kg   = pass ? nullptr : sgate;
            const float* Wq   = pass ? w_qh : w_ql;
            const float* Wk   = pass ? w_kl : w_kh;
            const float* Wv   = pass ? w_vl : w_vh;
            const float* Wp   = pass ? w_ph : w_pl;
            const float* resid = pass ? high : low;
            float* op = out + (size_t)pass * plane_f;
            k_proj<1><<<dim3(NB*NHW), dim3(256), 0, stream>>>(qsrc, qg, Wq, nullptr, nullptr, P0, nullptr, nullptr);
            k_proj<6><<<dim3(NB*NHW), dim3(256), 0, stream>>>(ksrc, kg, nullptr, Wk, Wv, nullptr, P1, P2);
            for (int b0 = 0; b0 < NB; b0 += nbc) {
                int nb = (NB - b0) < nbc ? (NB - b0) : nbc;
                size_t boff = (size_t)b0 * NPX * 64;
                k_attn<<<dim3(nb*NL), dim3(256), 0, stream>>>(P0 + boff, P1 + boff, P2 + boff, scr, nb);
                k_gather<<<dim3(nb*NHW), dim3(256), 0, stream>>>(scr, resid + boff, Wp, op + boff, nb);
            }
        }
    }
}